// Round 3
// baseline (250.552 us; speedup 1.0000x reference)
//
#include <hip/hip_runtime.h>
#include <math.h>

#define SEQ_N 2048
#define BATCH 2
#define CDIM 512
#define NHEADS 8
#define MROWS (BATCH * SEQ_N)            // 4096
#define QKV_N 1536                        // fused q|k|v output cols
#define KSPLIT 1536                       // K' = [hi|hi|lo] x [hi|lo|hi]
#define ATTN_SCALE 0.044194173824159216f  // 1/(8*sqrt(8))

typedef __attribute__((ext_vector_type(8))) __bf16 bf16x8;
typedef __attribute__((ext_vector_type(4))) float  f32x4;

static __device__ __forceinline__ unsigned short f2bf(float f) {
    __bf16 h = (__bf16)f;
    return __builtin_bit_cast(unsigned short, h);
}
static __device__ __forceinline__ float bf2f(unsigned short u) {
    return (float)__builtin_bit_cast(__bf16, u);
}

// async global->LDS, 16B per lane (dest must be wave-uniform base + lane*16)
static __device__ __forceinline__ void gll16(const void* g, void* l) {
    __builtin_amdgcn_global_load_lds(
        (const __attribute__((address_space(1))) unsigned int*)g,
        (__attribute__((address_space(3))) unsigned int*)l, 16, 0, 0);
}

// ---------------- LayerNorm -> bf16 hi/lo split ----------------
__global__ __launch_bounds__(128) void ln_split_kernel(
    const float* __restrict__ x, const float* __restrict__ g,
    const float* __restrict__ bta,
    unsigned short* __restrict__ xn_hi, unsigned short* __restrict__ xn_lo)
{
    int row = blockIdx.x;
    int t = threadIdx.x;
    const float4* xr = (const float4*)(x + (size_t)row * CDIM);
    float4 v = xr[t];
    float s  = v.x + v.y + v.z + v.w;
    float ss = v.x*v.x + v.y*v.y + v.z*v.z + v.w*v.w;
    #pragma unroll
    for (int off = 1; off <= 32; off <<= 1) {
        s  += __shfl_xor(s,  off);
        ss += __shfl_xor(ss, off);
    }
    __shared__ float red[4];
    if ((t & 63) == 0) { red[(t >> 6) * 2] = s; red[(t >> 6) * 2 + 1] = ss; }
    __syncthreads();
    s  = red[0] + red[2];
    ss = red[1] + red[3];
    float mean = s * (1.0f / CDIM);
    float var  = ss * (1.0f / CDIM) - mean * mean;
    float rstd = rsqrtf(var + 1e-5f);
    float4 gv = ((const float4*)g)[t];
    float4 bv = ((const float4*)bta)[t];
    float o[4];
    o[0] = (v.x - mean) * rstd * gv.x + bv.x;
    o[1] = (v.y - mean) * rstd * gv.y + bv.y;
    o[2] = (v.z - mean) * rstd * gv.z + bv.z;
    o[3] = (v.w - mean) * rstd * gv.w + bv.w;
    unsigned int ph[2], pl[2];
    #pragma unroll
    for (int i = 0; i < 2; ++i) {
        unsigned short h0 = f2bf(o[2*i]);
        unsigned short h1 = f2bf(o[2*i+1]);
        unsigned short l0 = f2bf(o[2*i]   - bf2f(h0));
        unsigned short l1 = f2bf(o[2*i+1] - bf2f(h1));
        ph[i] = (unsigned int)h0 | ((unsigned int)h1 << 16);
        pl[i] = (unsigned int)l0 | ((unsigned int)l1 << 16);
    }
    *(uint2*)&xn_hi[(size_t)row * CDIM + t * 4] = make_uint2(ph[0], ph[1]);
    *(uint2*)&xn_lo[(size_t)row * CDIM + t * 4] = make_uint2(pl[0], pl[1]);
}

// -------- weight transpose + hi/lo split into stacked-K bf16 layout --------
// BT'[n][k'] : k'<512 -> hi(W[k'][n]); k'<1024 -> lo(W[k'-512][n]); else hi(W[k'-1024][n])
__global__ __launch_bounds__(256) void wsplit_kernel(
    const float* __restrict__ wq, const float* __restrict__ wk,
    const float* __restrict__ wv, const float* __restrict__ wo,
    unsigned short* __restrict__ BTqkv, unsigned short* __restrict__ BTo)
{
    int m = blockIdx.z;                      // 0=q 1=k 2=v 3=o
    const float* W = (m == 0) ? wq : (m == 1) ? wk : (m == 2) ? wv : wo;
    int k0 = blockIdx.y * 64, c0 = blockIdx.x * 64;
    __shared__ float tile[64][68];
    int t = threadIdx.x;
    int r = t >> 4, ch = t & 15;
    #pragma unroll
    for (int i = 0; i < 4; ++i) {
        float4 v = *(const float4*)&W[(size_t)(k0 + r + i*16) * CDIM + c0 + ch*4];
        tile[r + i*16][ch*4 + 0] = v.x; tile[r + i*16][ch*4 + 1] = v.y;
        tile[r + i*16][ch*4 + 2] = v.z; tile[r + i*16][ch*4 + 3] = v.w;
    }
    __syncthreads();
    unsigned short* BT = (m < 3) ? BTqkv : BTo;
    int nbase = (m < 3) ? m * CDIM : 0;
    #pragma unroll
    for (int i = 0; i < 4; ++i) {
        int c  = c0 + r + i*16;              // output row (n)
        int kk = k0 + ch*4;                  // k within [0,512)
        unsigned int hi2[2], lo2[2];
        #pragma unroll
        for (int half = 0; half < 2; ++half) {
            unsigned short h[2], l[2];
            #pragma unroll
            for (int j = 0; j < 2; ++j) {
                float v = tile[ch*4 + half*2 + j][r + i*16];
                h[j] = f2bf(v);
                l[j] = f2bf(v - bf2f(h[j]));
            }
            hi2[half] = (unsigned int)h[0] | ((unsigned int)h[1] << 16);
            lo2[half] = (unsigned int)l[0] | ((unsigned int)l[1] << 16);
        }
        size_t ro = (size_t)(nbase + c) * KSPLIT;
        *(uint2*)&BT[ro + kk]        = make_uint2(hi2[0], hi2[1]);
        *(uint2*)&BT[ro + 512 + kk]  = make_uint2(lo2[0], lo2[1]);
        *(uint2*)&BT[ro + 1024 + kk] = make_uint2(hi2[0], hi2[1]);
    }
}

// ---------------- bf16 MFMA GEMM with stacked-K split ----------------
// C(M x N) = [A_hi|A_hi|A_lo](M x 1536) @ BT'^T(1536 x N) + bias
// BM=128 BN=64 BK=64, 256 threads = 4 waves (2x2), wave tile 64x32.
// outb!=null : bf16 out, pitch 1536, bias select b0/b1/b2 by col/512
// outb==null : f32 out, pitch 512, bias b0
__global__ __launch_bounds__(256) void gemm_split_kernel(
    const unsigned short* __restrict__ Ahi, const unsigned short* __restrict__ Alo,
    const unsigned short* __restrict__ BT,
    const float* __restrict__ b0, const float* __restrict__ b1,
    const float* __restrict__ b2,
    unsigned short* __restrict__ outb, float* __restrict__ outf)
{
    __shared__ unsigned short As[128 * 64];
    __shared__ unsigned short Bs[64 * 64];
    int tid = threadIdx.x;
    int l = tid & 63, w = tid >> 6;
    int am = w >> 1, an = w & 1;
    int m0 = blockIdx.y * 128, n0 = blockIdx.x * 64;

    f32x4 acc[4][2];
    #pragma unroll
    for (int fm = 0; fm < 4; ++fm)
        #pragma unroll
        for (int fn = 0; fn < 2; ++fn)
            acc[fm][fn] = (f32x4){0.f, 0.f, 0.f, 0.f};

    for (int kt = 0; kt < 24; ++kt) {
        int kp  = kt * 64;
        int seg = kp >> 9;                       // 0,1 -> A_hi ; 2 -> A_lo
        const unsigned short* Asrc = (seg < 2) ? Ahi : Alo;
        int ac0 = kp & 511;
        __syncthreads();
        #pragma unroll
        for (int i = 0; i < 4; ++i) {
            int c = tid + i * 256;               // 16B chunk id, wave-contiguous
            int row = c >> 3, c8 = c & 7;
            gll16(Asrc + (size_t)(m0 + row) * CDIM + ac0 + c8 * 8, &As[c * 8]);
        }
        #pragma unroll
        for (int i = 0; i < 2; ++i) {
            int c = tid + i * 256;
            int row = c >> 3, c8 = c & 7;
            gll16(BT + (size_t)(n0 + row) * KSPLIT + kp + c8 * 8, &Bs[c * 8]);
        }
        __syncthreads();                          // compiler drains vmcnt before barrier
        #pragma unroll
        for (int kc = 0; kc < 2; ++kc) {
            bf16x8 af[4], bfr[2];
            #pragma unroll
            for (int fm = 0; fm < 4; ++fm)
                af[fm] = *(const bf16x8*)&As[(am*64 + fm*16 + (l & 15)) * 64 + kc*32 + (l >> 4) * 8];
            #pragma unroll
            for (int fn = 0; fn < 2; ++fn)
                bfr[fn] = *(const bf16x8*)&Bs[(an*32 + fn*16 + (l & 15)) * 64 + kc*32 + (l >> 4) * 8];
            #pragma unroll
            for (int fm = 0; fm < 4; ++fm)
                #pragma unroll
                for (int fn = 0; fn < 2; ++fn)
                    acc[fm][fn] = __builtin_amdgcn_mfma_f32_16x16x32_bf16(
                        af[fm], bfr[fn], acc[fm][fn], 0, 0, 0);
        }
    }
    #pragma unroll
    for (int fm = 0; fm < 4; ++fm)
        #pragma unroll
        for (int fn = 0; fn < 2; ++fn)
            #pragma unroll
            for (int r = 0; r < 4; ++r) {
                int row = m0 + am*64 + fm*16 + (l >> 4) * 4 + r;
                int col = n0 + an*32 + fn*16 + (l & 15);
                float v = acc[fm][fn][r];
                if (outb) {
                    float bias = (col < 512) ? b0[col]
                               : (col < 1024) ? b1[col - 512] : b2[col - 1024];
                    outb[(size_t)row * QKV_N + col] = f2bf(v + bias);
                } else {
                    outf[(size_t)row * CDIM + col] = v + b0[col];
                }
            }
}

// ---------------- bf16 MFMA flash attention ----------------
// grid (B*H=16, N/64=32), 256 thr = 4 waves, wave owns 16 q-rows.
// VTs stores V^T with kv-chunk XOR-swizzled by d-chunk to kill the
// (d-chunk stride % 128B == 0) write bank conflict; reads apply same XOR.
__global__ __launch_bounds__(256) void attn_kernel(
    const unsigned short* __restrict__ qkv, const int* __restrict__ maskp,
    unsigned short* __restrict__ ao_hi, unsigned short* __restrict__ ao_lo)
{
    __shared__ unsigned short Ks[64 * 72];
    __shared__ unsigned short VTs[64 * 72];
    __shared__ unsigned short Ps[4][16 * 72];
    __shared__ float mskf[64];

    int tid = threadIdx.x, l = tid & 63, w = tid >> 6;
    int bh = blockIdx.x;
    int b = bh >> 3, head = bh & 7;
    int q0 = blockIdx.y * 64;
    size_t brow = (size_t)b * SEQ_N;
    const unsigned short* Qb = qkv + head * 64;
    const unsigned short* Kb = qkv + 512 + head * 64;
    const unsigned short* Vb = qkv + 1024 + head * 64;

    // Q fragments live in registers for the whole block
    bf16x8 qf[2];
    {
        int qrow = q0 + w * 16 + (l & 15);
        #pragma unroll
        for (int kc = 0; kc < 2; ++kc)
            qf[kc] = *(const bf16x8*)&Qb[(brow + qrow) * QKV_N + kc*32 + (l >> 4) * 8];
    }

    float m_i[4], l_i[4];
    f32x4 o[4];
    #pragma unroll
    for (int r = 0; r < 4; ++r) { m_i[r] = -1e30f; l_i[r] = 0.f; }
    #pragma unroll
    for (int nb = 0; nb < 4; ++nb) o[nb] = (f32x4){0.f, 0.f, 0.f, 0.f};

    for (int kv0 = 0; kv0 < SEQ_N; kv0 += 64) {
        __syncthreads();
        #pragma unroll
        for (int i = 0; i < 2; ++i) {            // K tile rows, direct
            int c = tid + i * 256;
            int row = c >> 3, c8 = c & 7;
            *(uint4*)&Ks[row * 72 + c8 * 8] =
                *(const uint4*)&Kb[(brow + kv0 + row) * QKV_N + c8 * 8];
        }
        #pragma unroll
        for (int i = 0; i < 2; ++i) {            // V tile, transposed into LDS
            int c = tid + i * 256;
            int row = c >> 3, c8 = c & 7;        // row = kv index, c8 = d-chunk
            uint4 vv = *(const uint4*)&Vb[(brow + kv0 + row) * QKV_N + c8 * 8];
            const unsigned short* pv = (const unsigned short*)&vv;
            int swc = ((row >> 3) ^ c8) & 7;     // swizzled kv-chunk
            #pragma unroll
            for (int j = 0; j < 8; ++j)
                VTs[(c8 * 8 + j) * 72 + swc * 8 + (row & 7)] = pv[j];
        }
        if (tid < 64) mskf[tid] = (float)maskp[b * SEQ_N + kv0 + tid];
        __syncthreads();

        // S = Q K^T  (rows: (l>>4)*4+r within wave's 16; cols: nb*16+(l&15))
        f32x4 s[4];
        #pragma unroll
        for (int nb = 0; nb < 4; ++nb) s[nb] = (f32x4){0.f, 0.f, 0.f, 0.f};
        #pragma unroll
        for (int kc = 0; kc < 2; ++kc)
            #pragma unroll
            for (int nb = 0; nb < 4; ++nb) {
                bf16x8 kf = *(const bf16x8*)&Ks[(nb*16 + (l & 15)) * 72 + kc*32 + (l >> 4) * 8];
                s[nb] = __builtin_amdgcn_mfma_f32_16x16x32_bf16(qf[kc], kf, s[nb], 0, 0, 0);
            }

        // mask(replace) + scale
        #pragma unroll
        for (int nb = 0; nb < 4; ++nb) {
            float mk = mskf[nb * 16 + (l & 15)];
            #pragma unroll
            for (int r = 0; r < 4; ++r)
                s[nb][r] = (mk != 0.f) ? s[nb][r] * ATTN_SCALE : -10000.f;
        }

        // online softmax (row = 16-lane group)
        #pragma unroll
        for (int r = 0; r < 4; ++r) {
            float rm = fmaxf(fmaxf(s[0][r], s[1][r]), fmaxf(s[2][r], s[3][r]));
            #pragma unroll
            for (int off = 1; off < 16; off <<= 1)
                rm = fmaxf(rm, __shfl_xor(rm, off));
            float mnew  = fmaxf(m_i[r], rm);
            float alpha = __expf(m_i[r] - mnew);
            float p[4], rs = 0.f;
            #pragma unroll
            for (int nb = 0; nb < 4; ++nb) { p[nb] = __expf(s[nb][r] - mnew); rs += p[nb]; }
            #pragma unroll
            for (int off = 1; off < 16; off <<= 1)
                rs += __shfl_xor(rs, off);
            l_i[r] = l_i[r] * alpha + rs;
            m_i[r] = mnew;
            #pragma unroll
            for (int nb = 0; nb < 4; ++nb) o[nb][r] *= alpha;
            int prow = (l >> 4) * 4 + r;
            #pragma unroll
            for (int nb = 0; nb < 4; ++nb)
                Ps[w][prow * 72 + nb * 16 + (l & 15)] = f2bf(p[nb]);
        }

        // O += P @ V   (A = P rows l&15 ; B = V[kv][d] via swizzled VT)
        #pragma unroll
        for (int kc = 0; kc < 2; ++kc) {
            bf16x8 pf = *(const bf16x8*)&Ps[w][(l & 15) * 72 + kc*32 + (l >> 4) * 8];
            int kb = kc * 4 + (l >> 4);          // logical kv-chunk
            #pragma unroll
            for (int nb = 0; nb < 4; ++nb) {
                int d = nb * 16 + (l & 15);
                bf16x8 vf = *(const bf16x8*)&VTs[d * 72 + ((kb ^ (d >> 3)) & 7) * 8];
                o[nb] = __builtin_amdgcn_mfma_f32_16x16x32_bf16(pf, vf, o[nb], 0, 0, 0);
            }
        }
    }

    // epilogue: normalize, hi/lo split for the (split) output projection
    #pragma unroll
    for (int r = 0; r < 4; ++r) {
        float invl = 1.f / l_i[r];
        int row = q0 + w * 16 + (l >> 4) * 4 + r;
        #pragma unroll
        for (int nb = 0; nb < 4; ++nb) {
            float v = o[nb][r] * invl;
            unsigned short h  = f2bf(v);
            unsigned short lo = f2bf(v - bf2f(h));
            size_t idx = (brow + row) * (size_t)CDIM + head * 64 + nb * 16 + (l & 15);
            ao_hi[idx] = h;
            ao_lo[idx] = lo;
        }
    }
}

extern "C" void kernel_launch(void* const* d_in, const int* in_sizes, int n_in,
                              void* d_out, int out_size, void* d_ws, size_t ws_size,
                              hipStream_t stream) {
    const float* x    = (const float*)d_in[0];
    const int*   mask = (const int*)  d_in[1];
    const float* ln_g = (const float*)d_in[2];
    const float* ln_b = (const float*)d_in[3];
    const float* wq   = (const float*)d_in[4];
    const float* bq   = (const float*)d_in[5];
    const float* wk   = (const float*)d_in[6];
    const float* bk   = (const float*)d_in[7];
    const float* wv   = (const float*)d_in[8];
    const float* bv   = (const float*)d_in[9];
    const float* wo   = (const float*)d_in[10];
    const float* bo   = (const float*)d_in[11];
    float* out = (float*)d_out;

    unsigned short* xn_hi = (unsigned short*)d_ws;
    unsigned short* xn_lo = xn_hi + (size_t)MROWS * CDIM;
    unsigned short* BTqkv = xn_lo + (size_t)MROWS * CDIM;
    unsigned short* BTo   = BTqkv + (size_t)QKV_N * KSPLIT;
    unsigned short* qkvb  = BTo   + (size_t)CDIM * KSPLIT;
    unsigned short* ao_hi = qkvb  + (size_t)MROWS * QKV_N;
    unsigned short* ao_lo = ao_hi + (size_t)MROWS * CDIM;

    ln_split_kernel<<<MROWS, 128, 0, stream>>>(x, ln_g, ln_b, xn_hi, xn_lo);
    wsplit_kernel<<<dim3(8, 8, 4), 256, 0, stream>>>(wq, wk, wv, wo, BTqkv, BTo);

    // fused QKV projection: M=4096, N=1536, K'=1536
    gemm_split_kernel<<<dim3(QKV_N / 64, MROWS / 128), 256, 0, stream>>>(
        xn_hi, xn_lo, BTqkv, bq, bk, bv, qkvb, nullptr);

    attn_kernel<<<dim3(BATCH * NHEADS, SEQ_N / 64), 256, 0, stream>>>(
        qkvb, mask, ao_hi, ao_lo);

    // output projection: M=4096, N=512, K'=1536
    gemm_split_kernel<<<dim3(CDIM / 64, MROWS / 128), 256, 0, stream>>>(
        ao_hi, ao_lo, BTo, bo, nullptr, nullptr, nullptr, out);
}

// Round 5
// 244.370 us; speedup vs baseline: 1.0253x; 1.0253x over previous
//
#include <hip/hip_runtime.h>
#include <math.h>

#define SEQ_N 2048
#define BATCH 2
#define CDIM 512
#define NHEADS 8
#define MROWS (BATCH * SEQ_N)            // 4096
#define QKV_N 1536                        // fused q|k|v output cols
#define KSPLIT 1536                       // K' = [hi|hi|lo] x [hi|lo|hi]
#define ATTN_SCALE 0.044194173824159216f  // 1/(8*sqrt(8))
#define BH (BATCH * NHEADS)               // 16
#define ROWS_ALL (BH * SEQ_N)             // 32768

typedef __attribute__((ext_vector_type(8))) __bf16 bf16x8;
typedef __attribute__((ext_vector_type(4))) float  f32x4;

static __device__ __forceinline__ unsigned short f2bf(float f) {
    __bf16 h = (__bf16)f;
    return __builtin_bit_cast(unsigned short, h);
}
static __device__ __forceinline__ float bf2f(unsigned short u) {
    return (float)__builtin_bit_cast(__bf16, u);
}

// async global->LDS, 16B per lane (dest must be wave-uniform base + lane*16)
static __device__ __forceinline__ void gll16(const void* g, void* l) {
    __builtin_amdgcn_global_load_lds(
        (const __attribute__((address_space(1))) unsigned int*)g,
        (__attribute__((address_space(3))) unsigned int*)l, 16, 0, 0);
}

// ---------------- LayerNorm -> bf16 hi/lo split ----------------
__global__ __launch_bounds__(128) void ln_split_kernel(
    const float* __restrict__ x, const float* __restrict__ g,
    const float* __restrict__ bta,
    unsigned short* __restrict__ xn_hi, unsigned short* __restrict__ xn_lo)
{
    int row = blockIdx.x;
    int t = threadIdx.x;
    const float4* xr = (const float4*)(x + (size_t)row * CDIM);
    float4 v = xr[t];
    float s  = v.x + v.y + v.z + v.w;
    float ss = v.x*v.x + v.y*v.y + v.z*v.z + v.w*v.w;
    #pragma unroll
    for (int off = 1; off <= 32; off <<= 1) {
        s  += __shfl_xor(s,  off);
        ss += __shfl_xor(ss, off);
    }
    __shared__ float red[4];
    if ((t & 63) == 0) { red[(t >> 6) * 2] = s; red[(t >> 6) * 2 + 1] = ss; }
    __syncthreads();
    s  = red[0] + red[2];
    ss = red[1] + red[3];
    float mean = s * (1.0f / CDIM);
    float var  = ss * (1.0f / CDIM) - mean * mean;
    float rstd = rsqrtf(var + 1e-5f);
    float4 gv = ((const float4*)g)[t];
    float4 bv = ((const float4*)bta)[t];
    float o[4];
    o[0] = (v.x - mean) * rstd * gv.x + bv.x;
    o[1] = (v.y - mean) * rstd * gv.y + bv.y;
    o[2] = (v.z - mean) * rstd * gv.z + bv.z;
    o[3] = (v.w - mean) * rstd * gv.w + bv.w;
    unsigned int ph[2], pl[2];
    #pragma unroll
    for (int i = 0; i < 2; ++i) {
        unsigned short h0 = f2bf(o[2*i]);
        unsigned short h1 = f2bf(o[2*i+1]);
        unsigned short l0 = f2bf(o[2*i]   - bf2f(h0));
        unsigned short l1 = f2bf(o[2*i+1] - bf2f(h1));
        ph[i] = (unsigned int)h0 | ((unsigned int)h1 << 16);
        pl[i] = (unsigned int)l0 | ((unsigned int)l1 << 16);
    }
    *(uint2*)&xn_hi[(size_t)row * CDIM + t * 4] = make_uint2(ph[0], ph[1]);
    *(uint2*)&xn_lo[(size_t)row * CDIM + t * 4] = make_uint2(pl[0], pl[1]);
}

// -------- weight transpose + hi/lo split into stacked-K bf16 layout --------
__global__ __launch_bounds__(256) void wsplit_kernel(
    const float* __restrict__ wq, const float* __restrict__ wk,
    const float* __restrict__ wv, const float* __restrict__ wo,
    unsigned short* __restrict__ BTqkv, unsigned short* __restrict__ BTo)
{
    int m = blockIdx.z;                      // 0=q 1=k 2=v 3=o
    const float* W = (m == 0) ? wq : (m == 1) ? wk : (m == 2) ? wv : wo;
    int k0 = blockIdx.y * 64, c0 = blockIdx.x * 64;
    __shared__ float tile[64][68];
    int t = threadIdx.x;
    int r = t >> 4, ch = t & 15;
    #pragma unroll
    for (int i = 0; i < 4; ++i) {
        float4 v = *(const float4*)&W[(size_t)(k0 + r + i*16) * CDIM + c0 + ch*4];
        tile[r + i*16][ch*4 + 0] = v.x; tile[r + i*16][ch*4 + 1] = v.y;
        tile[r + i*16][ch*4 + 2] = v.z; tile[r + i*16][ch*4 + 3] = v.w;
    }
    __syncthreads();
    unsigned short* BT = (m < 3) ? BTqkv : BTo;
    int nbase = (m < 3) ? m * CDIM : 0;
    #pragma unroll
    for (int i = 0; i < 4; ++i) {
        int c  = c0 + r + i*16;              // output row (n)
        int kk = k0 + ch*4;                  // k within [0,512)
        unsigned int hi2[2], lo2[2];
        #pragma unroll
        for (int half = 0; half < 2; ++half) {
            unsigned short h[2], l[2];
            #pragma unroll
            for (int j = 0; j < 2; ++j) {
                float v = tile[ch*4 + half*2 + j][r + i*16];
                h[j] = f2bf(v);
                l[j] = f2bf(v - bf2f(h[j]));
            }
            hi2[half] = (unsigned int)h[0] | ((unsigned int)h[1] << 16);
            lo2[half] = (unsigned int)l[0] | ((unsigned int)l[1] << 16);
        }
        size_t ro = (size_t)(nbase + c) * KSPLIT;
        *(uint2*)&BT[ro + kk]        = make_uint2(hi2[0], hi2[1]);
        *(uint2*)&BT[ro + 512 + kk]  = make_uint2(lo2[0], lo2[1]);
        *(uint2*)&BT[ro + 1024 + kk] = make_uint2(hi2[0], hi2[1]);
    }
}

// ---------------- bf16 MFMA GEMM with stacked-K split ----------------
// C(M x N) = [A_hi|A_hi|A_lo](M x 1536) @ BT'^T(1536 x N) + bias
// BM=128, BK=64. BN=128: 512 thr = 8 waves (2x4). BN=64: 256 thr = 4 waves (2x2).
// Wave tile 64x32, acc[4][2] either way; accumulation order identical.
template<int BN>
__global__ __launch_bounds__(BN == 128 ? 512 : 256) void gemm_split_kernel(
    const unsigned short* __restrict__ Ahi, const unsigned short* __restrict__ Alo,
    const unsigned short* __restrict__ BT,
    const float* __restrict__ b0, const float* __restrict__ b1,
    const float* __restrict__ b2,
    unsigned short* __restrict__ outb, float* __restrict__ outf)
{
    constexpr int NT  = (BN == 128) ? 512 : 256;   // threads
    constexpr int ACH = 1024 / NT;                 // A 16B-chunks per thread
    constexpr int BCH = (BN * 8) / NT;             // B 16B-chunks per thread
    __shared__ unsigned short As[128 * 64];
    __shared__ unsigned short Bs[BN * 64];
    int tid = threadIdx.x;
    int l = tid & 63, w = tid >> 6;
    int am = (BN == 128) ? (w >> 2) : (w >> 1);
    int an = (BN == 128) ? (w & 3)  : (w & 1);
    int m0 = blockIdx.y * 128, n0 = blockIdx.x * BN;

    f32x4 acc[4][2];
    #pragma unroll
    for (int fm = 0; fm < 4; ++fm)
        #pragma unroll
        for (int fn = 0; fn < 2; ++fn)
            acc[fm][fn] = (f32x4){0.f, 0.f, 0.f, 0.f};

    for (int kt = 0; kt < 24; ++kt) {
        int kp  = kt * 64;
        int seg = kp >> 9;                       // 0,1 -> A_hi ; 2 -> A_lo
        const unsigned short* Asrc = (seg < 2) ? Ahi : Alo;
        int ac0 = kp & 511;
        __syncthreads();
        #pragma unroll
        for (int i = 0; i < ACH; ++i) {
            int c = tid + i * NT;                // 16B chunk id, wave-contiguous
            int row = c >> 3, c8 = c & 7;
            gll16(Asrc + (size_t)(m0 + row) * CDIM + ac0 + c8 * 8, &As[c * 8]);
        }
        #pragma unroll
        for (int i = 0; i < BCH; ++i) {
            int c = tid + i * NT;
            int row = c >> 3, c8 = c & 7;
            gll16(BT + (size_t)(n0 + row) * KSPLIT + kp + c8 * 8, &Bs[c * 8]);
        }
        __syncthreads();                          // compiler drains vmcnt before barrier
        #pragma unroll
        for (int kc = 0; kc < 2; ++kc) {
            bf16x8 af[4], bfr[2];
            #pragma unroll
            for (int fm = 0; fm < 4; ++fm)
                af[fm] = *(const bf16x8*)&As[(am*64 + fm*16 + (l & 15)) * 64 + kc*32 + (l >> 4) * 8];
            #pragma unroll
            for (int fn = 0; fn < 2; ++fn)
                bfr[fn] = *(const bf16x8*)&Bs[(an*32 + fn*16 + (l & 15)) * 64 + kc*32 + (l >> 4) * 8];
            #pragma unroll
            for (int fm = 0; fm < 4; ++fm)
                #pragma unroll
                for (int fn = 0; fn < 2; ++fn)
                    acc[fm][fn] = __builtin_amdgcn_mfma_f32_16x16x32_bf16(
                        af[fm], bfr[fn], acc[fm][fn], 0, 0, 0);
        }
    }
    #pragma unroll
    for (int fm = 0; fm < 4; ++fm)
        #pragma unroll
        for (int fn = 0; fn < 2; ++fn)
            #pragma unroll
            for (int r = 0; r < 4; ++r) {
                int row = m0 + am*64 + fm*16 + (l >> 4) * 4 + r;
                int col = n0 + an*32 + fn*16 + (l & 15);
                float v = acc[fm][fn][r];
                if (outb) {
                    float bias = (col < 512) ? b0[col]
                               : (col < 1024) ? b1[col - 512] : b2[col - 1024];
                    outb[(size_t)row * QKV_N + col] = f2bf(v + bias);
                } else {
                    outf[(size_t)row * CDIM + col] = v + b0[col];
                }
            }
}

// ---------------- bf16 MFMA flash attention with KV-split ----------------
// grid (BH=16, N/64=32, S). 256 thr = 4 waves, wave owns 16 q-rows.
// S>1: write unnormalized partials (Opart,mpart,lpart); S==1: direct output.
__global__ __launch_bounds__(256) void attn_kernel(
    const unsigned short* __restrict__ qkv, const int* __restrict__ maskp,
    float* __restrict__ Opart, float* __restrict__ mpart, float* __restrict__ lpart,
    unsigned short* __restrict__ ao_hi, unsigned short* __restrict__ ao_lo)
{
    __shared__ unsigned short Ks[64 * 72];
    __shared__ unsigned short VTs[64 * 72];
    __shared__ unsigned short Ps[4][16 * 72];
    __shared__ float mskf[64];

    int tid = threadIdx.x, l = tid & 63, w = tid >> 6;
    int bh = blockIdx.x;
    int b = bh >> 3, head = bh & 7;
    int q0 = blockIdx.y * 64;
    int kvlen = SEQ_N / gridDim.z;
    int kvbeg = blockIdx.z * kvlen;
    size_t brow = (size_t)b * SEQ_N;
    const unsigned short* Qb = qkv + head * 64;
    const unsigned short* Kb = qkv + 512 + head * 64;
    const unsigned short* Vb = qkv + 1024 + head * 64;

    // Q fragments live in registers for the whole block
    bf16x8 qf[2];
    {
        int qrow = q0 + w * 16 + (l & 15);
        #pragma unroll
        for (int kc = 0; kc < 2; ++kc)
            qf[kc] = *(const bf16x8*)&Qb[(brow + qrow) * QKV_N + kc*32 + (l >> 4) * 8];
    }

    float m_i[4], l_i[4];
    f32x4 o[4];
    #pragma unroll
    for (int r = 0; r < 4; ++r) { m_i[r] = -1e30f; l_i[r] = 0.f; }
    #pragma unroll
    for (int nb = 0; nb < 4; ++nb) o[nb] = (f32x4){0.f, 0.f, 0.f, 0.f};

    for (int kv0 = kvbeg; kv0 < kvbeg + kvlen; kv0 += 64) {
        __syncthreads();
        #pragma unroll
        for (int i = 0; i < 2; ++i) {            // K tile rows, direct
            int c = tid + i * 256;
            int row = c >> 3, c8 = c & 7;
            *(uint4*)&Ks[row * 72 + c8 * 8] =
                *(const uint4*)&Kb[(brow + kv0 + row) * QKV_N + c8 * 8];
        }
        #pragma unroll
        for (int i = 0; i < 2; ++i) {            // V tile, transposed into LDS
            int c = tid + i * 256;
            int row = c >> 3, c8 = c & 7;        // row = kv index, c8 = d-chunk
            uint4 vv = *(const uint4*)&Vb[(brow + kv0 + row) * QKV_N + c8 * 8];
            const unsigned short* pv = (const unsigned short*)&vv;
            int swc = ((row >> 3) ^ c8) & 7;     // swizzled kv-chunk
            #pragma unroll
            for (int j = 0; j < 8; ++j)
                VTs[(c8 * 8 + j) * 72 + swc * 8 + (row & 7)] = pv[j];
        }
        if (tid < 64) mskf[tid] = (float)maskp[b * SEQ_N + kv0 + tid];
        __syncthreads();

        // S = Q K^T  (rows: (l>>4)*4+r within wave's 16; cols: nb*16+(l&15))
        f32x4 s[4];
        #pragma unroll
        for (int nb = 0; nb < 4; ++nb) s[nb] = (f32x4){0.f, 0.f, 0.f, 0.f};
        #pragma unroll
        for (int kc = 0; kc < 2; ++kc)
            #pragma unroll
            for (int nb = 0; nb < 4; ++nb) {
                bf16x8 kf = *(const bf16x8*)&Ks[(nb*16 + (l & 15)) * 72 + kc*32 + (l >> 4) * 8];
                s[nb] = __builtin_amdgcn_mfma_f32_16x16x32_bf16(qf[kc], kf, s[nb], 0, 0, 0);
            }

        // mask(replace) + scale
        #pragma unroll
        for (int nb = 0; nb < 4; ++nb) {
            float mk = mskf[nb * 16 + (l & 15)];
            #pragma unroll
            for (int r = 0; r < 4; ++r)
                s[nb][r] = (mk != 0.f) ? s[nb][r] * ATTN_SCALE : -10000.f;
        }

        // online softmax (row = 16-lane group)
        #pragma unroll
        for (int r = 0; r < 4; ++r) {
            float rm = fmaxf(fmaxf(s[0][r], s[1][r]), fmaxf(s[2][r], s[3][r]));
            #pragma unroll
            for (int off = 1; off < 16; off <<= 1)
                rm = fmaxf(rm, __shfl_xor(rm, off));
            float mnew  = fmaxf(m_i[r], rm);
            float alpha = __expf(m_i[r] - mnew);
            float p[4], rs = 0.f;
            #pragma unroll
            for (int nb = 0; nb < 4; ++nb) { p[nb] = __expf(s[nb][r] - mnew); rs += p[nb]; }
            #pragma unroll
            for (int off = 1; off < 16; off <<= 1)
                rs += __shfl_xor(rs, off);
            l_i[r] = l_i[r] * alpha + rs;
            m_i[r] = mnew;
            #pragma unroll
            for (int nb = 0; nb < 4; ++nb) o[nb][r] *= alpha;
            int prow = (l >> 4) * 4 + r;
            #pragma unroll
            for (int nb = 0; nb < 4; ++nb)
                Ps[w][prow * 72 + nb * 16 + (l & 15)] = f2bf(p[nb]);
        }

        // O += P @ V   (A = P rows l&15 ; B = V[kv][d] via swizzled VT)
        #pragma unroll
        for (int kc = 0; kc < 2; ++kc) {
            bf16x8 pf = *(const bf16x8*)&Ps[w][(l & 15) * 72 + kc*32 + (l >> 4) * 8];
            int kb = kc * 4 + (l >> 4);          // logical kv-chunk
            #pragma unroll
            for (int nb = 0; nb < 4; ++nb) {
                int d = nb * 16 + (l & 15);
                bf16x8 vf = *(const bf16x8*)&VTs[d * 72 + ((kb ^ (d >> 3)) & 7) * 8];
                o[nb] = __builtin_amdgcn_mfma_f32_16x16x32_bf16(pf, vf, o[nb], 0, 0, 0);
            }
        }
    }

    if (Opart) {
        // partial epilogue: unnormalized O + (m,l) per row
        int part = blockIdx.z * BH + bh;
        #pragma unroll
        for (int r = 0; r < 4; ++r) {
            int row = q0 + w * 16 + (l >> 4) * 4 + r;
            size_t rbase = ((size_t)part * SEQ_N + row) * 64;
            #pragma unroll
            for (int nb = 0; nb < 4; ++nb)
                Opart[rbase + nb * 16 + (l & 15)] = o[nb][r];
            if ((l & 15) == 0) {
                mpart[(size_t)part * SEQ_N + row] = m_i[r];
                lpart[(size_t)part * SEQ_N + row] = l_i[r];
            }
        }
    } else {
        // direct epilogue: normalize, hi/lo split
        #pragma unroll
        for (int r = 0; r < 4; ++r) {
            float invl = 1.f / l_i[r];
            int row = q0 + w * 16 + (l >> 4) * 4 + r;
            #pragma unroll
            for (int nb = 0; nb < 4; ++nb) {
                float v = o[nb][r] * invl;
                unsigned short h  = f2bf(v);
                unsigned short lo = f2bf(v - bf2f(h));
                size_t idx = (brow + row) * (size_t)CDIM + head * 64 + nb * 16 + (l & 15);
                ao_hi[idx] = h;
                ao_lo[idx] = lo;
            }
        }
    }
}

// ---------------- combine partials -> ao_hi/ao_lo ----------------
// 256 thr: 8 threads per row (8 f32 each), 32 rows per block. grid = 32768/32.
__global__ __launch_bounds__(256) void combine_kernel(
    const float* __restrict__ Opart, const float* __restrict__ mpart,
    const float* __restrict__ lpart, int S,
    unsigned short* __restrict__ ao_hi, unsigned short* __restrict__ ao_lo)
{
    int t = threadIdx.x;
    int row = blockIdx.x * 32 + (t >> 3);       // bh*2048 + n
    int d0 = (t & 7) * 8;
    float ms = -3.0e38f;
    for (int s = 0; s < S; ++s)
        ms = fmaxf(ms, mpart[(size_t)s * ROWS_ALL + row]);
    float L = 0.f;
    float acc[8] = {0.f,0.f,0.f,0.f,0.f,0.f,0.f,0.f};
    for (int s = 0; s < S; ++s) {
        float wgt = __expf(mpart[(size_t)s * ROWS_ALL + row] - ms);
        L = fmaf(lpart[(size_t)s * ROWS_ALL + row], wgt, L);
        const float4* op = (const float4*)&Opart[((size_t)s * ROWS_ALL + row) * 64 + d0];
        float4 a = op[0], c = op[1];
        acc[0] = fmaf(a.x, wgt, acc[0]); acc[1] = fmaf(a.y, wgt, acc[1]);
        acc[2] = fmaf(a.z, wgt, acc[2]); acc[3] = fmaf(a.w, wgt, acc[3]);
        acc[4] = fmaf(c.x, wgt, acc[4]); acc[5] = fmaf(c.y, wgt, acc[5]);
        acc[6] = fmaf(c.z, wgt, acc[6]); acc[7] = fmaf(c.w, wgt, acc[7]);
    }
    float inv = 1.f / L;
    int bh = row >> 11, n = row & 2047;
    int b = bh >> 3, h = bh & 7;
    size_t oidx = ((size_t)(b * SEQ_N + n)) * CDIM + h * 64 + d0;
    unsigned short hs[8], ls[8];
    #pragma unroll
    for (int j = 0; j < 8; ++j) {
        float v = acc[j] * inv;
        hs[j] = f2bf(v);
        ls[j] = f2bf(v - bf2f(hs[j]));
    }
    *(uint4*)&ao_hi[oidx] = *(uint4*)hs;
    *(uint4*)&ao_lo[oidx] = *(uint4*)ls;
}

extern "C" void kernel_launch(void* const* d_in, const int* in_sizes, int n_in,
                              void* d_out, int out_size, void* d_ws, size_t ws_size,
                              hipStream_t stream) {
    const float* x    = (const float*)d_in[0];
    const int*   mask = (const int*)  d_in[1];
    const float* ln_g = (const float*)d_in[2];
    const float* ln_b = (const float*)d_in[3];
    const float* wq   = (const float*)d_in[4];
    const float* bq   = (const float*)d_in[5];
    const float* wk   = (const float*)d_in[6];
    const float* bk   = (const float*)d_in[7];
    const float* wv   = (const float*)d_in[8];
    const float* bv   = (const float*)d_in[9];
    const float* wo   = (const float*)d_in[10];
    const float* bo   = (const float*)d_in[11];
    float* out = (float*)d_out;

    unsigned short* xn_hi = (unsigned short*)d_ws;
    unsigned short* xn_lo = xn_hi + (size_t)MROWS * CDIM;
    unsigned short* BTqkv = xn_lo + (size_t)MROWS * CDIM;
    unsigned short* BTo   = BTqkv + (size_t)QKV_N * KSPLIT;
    unsigned short* qkvb  = BTo   + (size_t)CDIM * KSPLIT;
    unsigned short* ao_hi = qkvb  + (size_t)MROWS * QKV_N;
    unsigned short* ao_lo = ao_hi + (size_t)MROWS * CDIM;
    unsigned short* ws_end = ao_lo + (size_t)MROWS * CDIM;

    size_t base_bytes = (size_t)((char*)ws_end - (char*)d_ws);
    const size_t part_bytes = (size_t)ROWS_ALL * (64 + 2) * 4;  // O + m + l per split
    int S = 1;
    if (base_bytes + 4 * part_bytes <= ws_size) S = 4;
    else if (base_bytes + 2 * part_bytes <= ws_size) S = 2;

    float* Opart = (float*)ws_end;                          // base offset is 16B-aligned
    float* mpart = Opart + (size_t)S * ROWS_ALL * 64;
    float* lpart = mpart + (size_t)S * ROWS_ALL;

    ln_split_kernel<<<MROWS, 128, 0, stream>>>(x, ln_g, ln_b, xn_hi, xn_lo);
    wsplit_kernel<<<dim3(8, 8, 4), 256, 0, stream>>>(wq, wk, wv, wo, BTqkv, BTo);

    // fused QKV projection: M=4096, N=1536, K'=1536  (BN=128, 8 waves)
    gemm_split_kernel<128><<<dim3(QKV_N / 128, MROWS / 128), 512, 0, stream>>>(
        xn_hi, xn_lo, BTqkv, bq, bk, bv, qkvb, nullptr);

    if (S > 1) {
        attn_kernel<<<dim3(BH, SEQ_N / 64, S), 256, 0, stream>>>(
            qkvb, mask, Opart, mpart, lpart, nullptr, nullptr);
        combine_kernel<<<ROWS_ALL / 32, 256, 0, stream>>>(
            Opart, mpart, lpart, S, ao_hi, ao_lo);
    } else {
        attn_kernel<<<dim3(BH, SEQ_N / 64, 1), 256, 0, stream>>>(
            qkvb, mask, nullptr, nullptr, nullptr, ao_hi, ao_lo);
    }

    // output projection: M=4096, N=512, K'=1536  (BN=64, 4 waves)
    gemm_split_kernel<64><<<dim3(CDIM / 64, MROWS / 128), 256, 0, stream>>>(
        ao_hi, ao_lo, BTo, bo, nullptr, nullptr, nullptr, out);
}

// Round 9
// 226.706 us; speedup vs baseline: 1.1052x; 1.0779x over previous
//
#include <hip/hip_runtime.h>
#include <math.h>

#define SEQ_N 2048
#define BATCH 2
#define CDIM 512
#define NHEADS 8
#define MROWS (BATCH * SEQ_N)            // 4096
#define QKV_N 1536                        // fused q|k|v output cols
#define KSPLIT 1536                       // K' = [hi|hi|lo] x [hi|lo|hi]
#define ATTN_SCALE 0.044194173824159216f  // 1/(8*sqrt(8))
#define LOG2E 1.4426950408889634f
#define SC2 (ATTN_SCALE * LOG2E)          // scale folded with log2(e): p = 2^(s*SC2 - m2)
#define MASK2 (-10000.0f * LOG2E)         // mask-replace value in log2 units
#define BH (BATCH * NHEADS)               // 16
#define ROWS_ALL (BH * SEQ_N)             // 32768

typedef __attribute__((ext_vector_type(8))) __bf16 bf16x8;
typedef __attribute__((ext_vector_type(4))) float  f32x4;

static __device__ __forceinline__ unsigned short f2bf(float f) {
    __bf16 h = (__bf16)f;
    return __builtin_bit_cast(unsigned short, h);
}
static __device__ __forceinline__ float bf2f(unsigned short u) {
    return (float)__builtin_bit_cast(__bf16, u);
}

// async global->LDS, 16B per lane (dest must be wave-uniform base + lane*16)
static __device__ __forceinline__ void gll16(const void* g, void* l) {
    __builtin_amdgcn_global_load_lds(
        (const __attribute__((address_space(1))) unsigned int*)g,
        (__attribute__((address_space(3))) unsigned int*)l, 16, 0, 0);
}

// ---------------- LayerNorm -> bf16 hi/lo split ----------------
__global__ __launch_bounds__(128) void ln_split_kernel(
    const float* __restrict__ x, const float* __restrict__ g,
    const float* __restrict__ bta,
    unsigned short* __restrict__ xn_hi, unsigned short* __restrict__ xn_lo)
{
    int row = blockIdx.x;
    int t = threadIdx.x;
    const float4* xr = (const float4*)(x + (size_t)row * CDIM);
    float4 v = xr[t];
    float s  = v.x + v.y + v.z + v.w;
    float ss = v.x*v.x + v.y*v.y + v.z*v.z + v.w*v.w;
    #pragma unroll
    for (int off = 1; off <= 32; off <<= 1) {
        s  += __shfl_xor(s,  off);
        ss += __shfl_xor(ss, off);
    }
    __shared__ float red[4];
    if ((t & 63) == 0) { red[(t >> 6) * 2] = s; red[(t >> 6) * 2 + 1] = ss; }
    __syncthreads();
    s  = red[0] + red[2];
    ss = red[1] + red[3];
    float mean = s * (1.0f / CDIM);
    float var  = ss * (1.0f / CDIM) - mean * mean;
    float rstd = rsqrtf(var + 1e-5f);
    float4 gv = ((const float4*)g)[t];
    float4 bv = ((const float4*)bta)[t];
    float o[4];
    o[0] = (v.x - mean) * rstd * gv.x + bv.x;
    o[1] = (v.y - mean) * rstd * gv.y + bv.y;
    o[2] = (v.z - mean) * rstd * gv.z + bv.z;
    o[3] = (v.w - mean) * rstd * gv.w + bv.w;
    unsigned int ph[2], pl[2];
    #pragma unroll
    for (int i = 0; i < 2; ++i) {
        unsigned short h0 = f2bf(o[2*i]);
        unsigned short h1 = f2bf(o[2*i+1]);
        unsigned short l0 = f2bf(o[2*i]   - bf2f(h0));
        unsigned short l1 = f2bf(o[2*i+1] - bf2f(h1));
        ph[i] = (unsigned int)h0 | ((unsigned int)h1 << 16);
        pl[i] = (unsigned int)l0 | ((unsigned int)l1 << 16);
    }
    *(uint2*)&xn_hi[(size_t)row * CDIM + t * 4] = make_uint2(ph[0], ph[1]);
    *(uint2*)&xn_lo[(size_t)row * CDIM + t * 4] = make_uint2(pl[0], pl[1]);
}

// -------- weight transpose + hi/lo split into stacked-K bf16 layout --------
__global__ __launch_bounds__(256) void wsplit_kernel(
    const float* __restrict__ wq, const float* __restrict__ wk,
    const float* __restrict__ wv, const float* __restrict__ wo,
    unsigned short* __restrict__ BTqkv, unsigned short* __restrict__ BTo)
{
    int m = blockIdx.z;                      // 0=q 1=k 2=v 3=o
    const float* W = (m == 0) ? wq : (m == 1) ? wk : (m == 2) ? wv : wo;
    int k0 = blockIdx.y * 64, c0 = blockIdx.x * 64;
    __shared__ float tile[64][68];
    int t = threadIdx.x;
    int r = t >> 4, ch = t & 15;
    #pragma unroll
    for (int i = 0; i < 4; ++i) {
        float4 v = *(const float4*)&W[(size_t)(k0 + r + i*16) * CDIM + c0 + ch*4];
        tile[r + i*16][ch*4 + 0] = v.x; tile[r + i*16][ch*4 + 1] = v.y;
        tile[r + i*16][ch*4 + 2] = v.z; tile[r + i*16][ch*4 + 3] = v.w;
    }
    __syncthreads();
    unsigned short* BT = (m < 3) ? BTqkv : BTo;
    int nbase = (m < 3) ? m * CDIM : 0;
    #pragma unroll
    for (int i = 0; i < 4; ++i) {
        int c  = c0 + r + i*16;              // output row (n)
        int kk = k0 + ch*4;                  // k within [0,512)
        unsigned int hi2[2], lo2[2];
        #pragma unroll
        for (int half = 0; half < 2; ++half) {
            unsigned short h[2], l[2];
            #pragma unroll
            for (int j = 0; j < 2; ++j) {
                float v = tile[ch*4 + half*2 + j][r + i*16];
                h[j] = f2bf(v);
                l[j] = f2bf(v - bf2f(h[j]));
            }
            hi2[half] = (unsigned int)h[0] | ((unsigned int)h[1] << 16);
            lo2[half] = (unsigned int)l[0] | ((unsigned int)l[1] << 16);
        }
        size_t ro = (size_t)(nbase + c) * KSPLIT;
        *(uint2*)&BT[ro + kk]        = make_uint2(hi2[0], hi2[1]);
        *(uint2*)&BT[ro + 512 + kk]  = make_uint2(lo2[0], lo2[1]);
        *(uint2*)&BT[ro + 1024 + kk] = make_uint2(hi2[0], hi2[1]);
    }
}

// ---------------- bf16 MFMA GEMM, m97 structure ----------------
// C(M x N) = [A_hi|A_hi|A_lo](M x 1536) @ BT'^T(1536 x N) + bias
// BM=128, BK=64, 256 threads = 4 waves (2x2).
// BN=128: wave tile 64x64, acc[4][4] (m97).  BN=64: wave tile 64x32, acc[4][2].
template<int BN>
__global__ __launch_bounds__(256) void gemm_split_kernel(
    const unsigned short* __restrict__ Ahi, const unsigned short* __restrict__ Alo,
    const unsigned short* __restrict__ BT,
    const float* __restrict__ b0, const float* __restrict__ b1,
    const float* __restrict__ b2,
    unsigned short* __restrict__ outb, float* __restrict__ outf)
{
    constexpr int FN  = BN / 32;                 // 4 (BN=128) or 2 (BN=64)
    constexpr int WNS = BN / 2;                  // wave n-span: 64 or 32
    constexpr int BCH = (BN * 8) / 256;          // B 16B-chunks per thread: 4 or 2
    __shared__ unsigned short As[128 * 64];
    __shared__ unsigned short Bs[BN * 64];
    int tid = threadIdx.x;
    int l = tid & 63, w = tid >> 6;
    int am = w >> 1, an = w & 1;
    int m0 = blockIdx.y * 128, n0 = blockIdx.x * BN;

    f32x4 acc[4][FN];
    #pragma unroll
    for (int fm = 0; fm < 4; ++fm)
        #pragma unroll
        for (int fn = 0; fn < FN; ++fn)
            acc[fm][fn] = (f32x4){0.f, 0.f, 0.f, 0.f};

    for (int kt = 0; kt < 24; ++kt) {
        int kp  = kt * 64;
        int seg = kp >> 9;                       // 0,1 -> A_hi ; 2 -> A_lo
        const unsigned short* Asrc = (seg < 2) ? Ahi : Alo;
        int ac0 = kp & 511;
        __syncthreads();
        #pragma unroll
        for (int i = 0; i < 4; ++i) {
            int c = tid + i * 256;               // 16B chunk id, wave-contiguous
            int row = c >> 3, c8 = c & 7;
            gll16(Asrc + (size_t)(m0 + row) * CDIM + ac0 + c8 * 8, &As[c * 8]);
        }
        #pragma unroll
        for (int i = 0; i < BCH; ++i) {
            int c = tid + i * 256;
            int row = c >> 3, c8 = c & 7;
            gll16(BT + (size_t)(n0 + row) * KSPLIT + kp + c8 * 8, &Bs[c * 8]);
        }
        __syncthreads();                          // compiler drains vmcnt before barrier
        #pragma unroll
        for (int kc = 0; kc < 2; ++kc) {
            bf16x8 af[4], bfr[FN];
            #pragma unroll
            for (int fm = 0; fm < 4; ++fm)
                af[fm] = *(const bf16x8*)&As[(am*64 + fm*16 + (l & 15)) * 64 + kc*32 + (l >> 4) * 8];
            #pragma unroll
            for (int fn = 0; fn < FN; ++fn)
                bfr[fn] = *(const bf16x8*)&Bs[(an*WNS + fn*16 + (l & 15)) * 64 + kc*32 + (l >> 4) * 8];
            #pragma unroll
            for (int fm = 0; fm < 4; ++fm)
                #pragma unroll
                for (int fn = 0; fn < FN; ++fn)
                    acc[fm][fn] = __builtin_amdgcn_mfma_f32_16x16x32_bf16(
                        af[fm], bfr[fn], acc[fm][fn], 0, 0, 0);
        }
    }
    #pragma unroll
    for (int fm = 0; fm < 4; ++fm)
        #pragma unroll
        for (int fn = 0; fn < FN; ++fn)
            #pragma unroll
            for (int r = 0; r < 4; ++r) {
                int row = m0 + am*64 + fm*16 + (l >> 4) * 4 + r;
                int col = n0 + an*WNS + fn*16 + (l & 15);
                float v = acc[fm][fn][r];
                if (outb) {
                    float bias = (col < 512) ? b0[col]
                               : (col < 1024) ? b1[col - 512] : b2[col - 1024];
                    outb[(size_t)row * QKV_N + col] = f2bf(v + bias);
                } else {
                    outf[(size_t)row * CDIM + col] = v + b0[col];
                }
            }
}

// ---------------- bf16 MFMA flash attention with KV-split ----------------
// grid (BH=16, N/128=16, S). 512 thr = 8 waves, wave owns 16 q-rows (QBLK=128).
// 8 waves share one K/V staging tile; LDS 37.1 KB -> 4 blocks/CU = 32 waves/CU.
// Row-sum via MFMA against a ones-fragment; softmax in log2 domain.
__global__ __launch_bounds__(512) void attn_kernel(
    const unsigned short* __restrict__ qkv, const int* __restrict__ maskp,
    float* __restrict__ Opart, float* __restrict__ mpart, float* __restrict__ lpart,
    unsigned short* __restrict__ ao_hi, unsigned short* __restrict__ ao_lo)
{
    __shared__ unsigned short Ks[64 * 72];
    __shared__ unsigned short VTs[64 * 72];
    __shared__ unsigned short Ps[8][16 * 72];
    __shared__ float mskf[64];

    int tid = threadIdx.x, l = tid & 63, w = tid >> 6;   // w = 0..7
    int bh = blockIdx.x;
    int b = bh >> 3, head = bh & 7;
    int q0 = blockIdx.y * 128;
    int kvlen = SEQ_N / gridDim.z;
    int kvbeg = blockIdx.z * kvlen;
    size_t brow = (size_t)b * SEQ_N;
    const unsigned short* Qb = qkv + head * 64;
    const unsigned short* Kb = qkv + 512 + head * 64;
    const unsigned short* Vb = qkv + 1024 + head * 64;

    const __bf16 one_bf = (__bf16)1.0f;
    bf16x8 onesf = {one_bf, one_bf, one_bf, one_bf, one_bf, one_bf, one_bf, one_bf};

    // Q fragments live in registers for the whole block
    bf16x8 qf[2];
    {
        int qrow = q0 + w * 16 + (l & 15);
        #pragma unroll
        for (int kc = 0; kc < 2; ++kc)
            qf[kc] = *(const bf16x8*)&Qb[(brow + qrow) * QKV_N + kc*32 + (l >> 4) * 8];
    }

    float m_i[4];
    f32x4 o[4], osum;
    #pragma unroll
    for (int r = 0; r < 4; ++r) m_i[r] = -1e30f;
    osum = (f32x4){0.f, 0.f, 0.f, 0.f};
    #pragma unroll
    for (int nb = 0; nb < 4; ++nb) o[nb] = (f32x4){0.f, 0.f, 0.f, 0.f};

    for (int kv0 = kvbeg; kv0 < kvbeg + kvlen; kv0 += 64) {
        __syncthreads();
        {                                        // K tile rows, direct (512 chunks, 512 thr)
            int row = tid >> 3, c8 = tid & 7;
            *(uint4*)&Ks[row * 72 + c8 * 8] =
                *(const uint4*)&Kb[(brow + kv0 + row) * QKV_N + c8 * 8];
        }
        {                                        // V tile, transposed into LDS
            int row = tid >> 3, c8 = tid & 7;    // row = kv index, c8 = d-chunk
            uint4 vv = *(const uint4*)&Vb[(brow + kv0 + row) * QKV_N + c8 * 8];
            const unsigned short* pv = (const unsigned short*)&vv;
            int swc = ((row >> 3) ^ c8) & 7;     // swizzled kv-chunk
            #pragma unroll
            for (int j = 0; j < 8; ++j)
                VTs[(c8 * 8 + j) * 72 + swc * 8 + (row & 7)] = pv[j];
        }
        if (tid < 64) mskf[tid] = (float)maskp[b * SEQ_N + kv0 + tid];
        __syncthreads();

        // S = Q K^T  (rows: (l>>4)*4+r within wave's 16; cols: nb*16+(l&15))
        f32x4 s[4];
        #pragma unroll
        for (int nb = 0; nb < 4; ++nb) s[nb] = (f32x4){0.f, 0.f, 0.f, 0.f};
        #pragma unroll
        for (int kc = 0; kc < 2; ++kc)
            #pragma unroll
            for (int nb = 0; nb < 4; ++nb) {
                bf16x8 kf = *(const bf16x8*)&Ks[(nb*16 + (l & 15)) * 72 + kc*32 + (l >> 4) * 8];
                s[nb] = __builtin_amdgcn_mfma_f32_16x16x32_bf16(qf[kc], kf, s[nb], 0, 0, 0);
            }

        // mask(replace) + scale, log2 domain
        #pragma unroll
        for (int nb = 0; nb < 4; ++nb) {
            float mk = mskf[nb * 16 + (l & 15)];
            #pragma unroll
            for (int r = 0; r < 4; ++r)
                s[nb][r] = (mk != 0.f) ? s[nb][r] * SC2 : MASK2;
        }

        // online softmax: max-reduce only (sum comes from the ones-MFMA)
        #pragma unroll
        for (int r = 0; r < 4; ++r) {
            float rm = fmaxf(fmaxf(s[0][r], s[1][r]), fmaxf(s[2][r], s[3][r]));
            #pragma unroll
            for (int off = 1; off < 16; off <<= 1)
                rm = fmaxf(rm, __shfl_xor(rm, off));
            float mnew  = fmaxf(m_i[r], rm);
            float alpha = exp2f(m_i[r] - mnew);
            m_i[r] = mnew;
            int prow = (l >> 4) * 4 + r;
            #pragma unroll
            for (int nb = 0; nb < 4; ++nb) {
                float p = exp2f(s[nb][r] - mnew);
                Ps[w][prow * 72 + nb * 16 + (l & 15)] = f2bf(p);
                o[nb][r] *= alpha;
            }
            osum[r] *= alpha;
        }

        // O += P @ V ; osum += P @ ones   (A = P rows l&15 ; B via swizzled VT)
        #pragma unroll
        for (int kc = 0; kc < 2; ++kc) {
            bf16x8 pf = *(const bf16x8*)&Ps[w][(l & 15) * 72 + kc*32 + (l >> 4) * 8];
            osum = __builtin_amdgcn_mfma_f32_16x16x32_bf16(pf, onesf, osum, 0, 0, 0);
            int kb = kc * 4 + (l >> 4);          // logical kv-chunk
            #pragma unroll
            for (int nb = 0; nb < 4; ++nb) {
                int d = nb * 16 + (l & 15);
                bf16x8 vf = *(const bf16x8*)&VTs[d * 72 + ((kb ^ (d >> 3)) & 7) * 8];
                o[nb] = __builtin_amdgcn_mfma_f32_16x16x32_bf16(pf, vf, o[nb], 0, 0, 0);
            }
        }
    }

    if (Opart) {
        // partial epilogue: unnormalized O + (m2,l) per row (m in log2 units)
        int part = blockIdx.z * BH + bh;
        #pragma unroll
        for (int r = 0; r < 4; ++r) {
            int row = q0 + w * 16 + (l >> 4) * 4 + r;
            size_t rbase = ((size_t)part * SEQ_N + row) * 64;
            #pragma unroll
            for (int nb = 0; nb < 4; ++nb)
                Opart[rbase + nb * 16 + (l & 15)] = o[nb][r];
            if ((l & 15) == 0) {
                mpart[(size_t)part * SEQ_N + row] = m_i[r];
                lpart[(size_t)part * SEQ_N + row] = osum[r];
            }
        }
    } else {
        // direct epilogue: normalize, hi/lo split
        #pragma unroll
        for (int r = 0; r < 4; ++r) {
            float invl = 1.f / osum[r];
            int row = q0 + w * 16 + (l >> 4) * 4 + r;
            #pragma unroll
            for (int nb = 0; nb < 4; ++nb) {
                float v = o[nb][r] * invl;
                unsigned short h  = f2bf(v);
                unsigned short lo = f2bf(v - bf2f(h));
                size_t idx = (brow + row) * (size_t)CDIM + head * 64 + nb * 16 + (l & 15);
                ao_hi[idx] = h;
                ao_lo[idx] = lo;
            }
        }
    }
}

// ---------------- combine partials -> ao_hi/ao_lo ----------------
// 256 thr: 8 threads per row (8 f32 each), 32 rows per block. grid = 32768/32.
__global__ __launch_bounds__(256) void combine_kernel(
    const float* __restrict__ Opart, const float* __restrict__ mpart,
    const float* __restrict__ lpart, int S,
    unsigned short* __restrict__ ao_hi, unsigned short* __restrict__ ao_lo)
{
    int t = threadIdx.x;
    int row = blockIdx.x * 32 + (t >> 3);       // bh*2048 + n
    int d0 = (t & 7) * 8;
    float ms = -3.0e38f;
    for (int s = 0; s < S; ++s)
        ms = fmaxf(ms, mpart[(size_t)s * ROWS_ALL + row]);
    float L = 0.f;
    float acc[8] = {0.f,0.f,0.f,0.f,0.f,0.f,0.f,0.f};
    for (int s = 0; s < S; ++s) {
        float wgt = exp2f(mpart[(size_t)s * ROWS_ALL + row] - ms);  // log2-domain m
        L = fmaf(lpart[(size_t)s * ROWS_ALL + row], wgt, L);
        const float4* op = (const float4*)&Opart[((size_t)s * ROWS_ALL + row) * 64 + d0];
        float4 a = op[0], c = op[1];
        acc[0] = fmaf(a.x, wgt, acc[0]); acc[1] = fmaf(a.y, wgt, acc[1]);
        acc[2] = fmaf(a.z, wgt, acc[2]); acc[3] = fmaf(a.w, wgt, acc[3]);
        acc[4] = fmaf(c.x, wgt, acc[4]); acc[5] = fmaf(c.y, wgt, acc[5]);
        acc[6] = fmaf(c.z, wgt, acc[6]); acc[7] = fmaf(c.w, wgt, acc[7]);
    }
    float inv = 1.f / L;
    int bh = row >> 11, n = row & 2047;
    int b = bh >> 3, h = bh & 7;
    size_t oidx = ((size_t)(b * SEQ_N + n)) * CDIM + h * 64 + d0;
    unsigned short hs[8], ls[8];
    #pragma unroll
    for (int j = 0; j < 8; ++j) {
        float v = acc[j] * inv;
        hs[j] = f2bf(v);
        ls[j] = f2bf(v - bf2f(hs[j]));
    }
    *(uint4*)&ao_hi[oidx] = *(uint4*)hs;
    *(uint4*)&ao_lo[oidx] = *(uint4*)ls;
}

extern "C" void kernel_launch(void* const* d_in, const int* in_sizes, int n_in,
                              void* d_out, int out_size, void* d_ws, size_t ws_size,
                              hipStream_t stream) {
    const float* x    = (const float*)d_in[0];
    const int*   mask = (const int*)  d_in[1];
    const float* ln_g = (const float*)d_in[2];
    const float* ln_b = (const float*)d_in[3];
    const float* wq   = (const float*)d_in[4];
    const float* bq   = (const float*)d_in[5];
    const float* wk   = (const float*)d_in[6];
    const float* bk   = (const float*)d_in[7];
    const float* wv   = (const float*)d_in[8];
    const float* bv   = (const float*)d_in[9];
    const float* wo   = (const float*)d_in[10];
    const float* bo   = (const float*)d_in[11];
    float* out = (float*)d_out;

    unsigned short* xn_hi = (unsigned short*)d_ws;
    unsigned short* xn_lo = xn_hi + (size_t)MROWS * CDIM;
    unsigned short* BTqkv = xn_lo + (size_t)MROWS * CDIM;
    unsigned short* BTo   = BTqkv + (size_t)QKV_N * KSPLIT;
    unsigned short* qkvb  = BTo   + (size_t)CDIM * KSPLIT;
    unsigned short* ao_hi = qkvb  + (size_t)MROWS * QKV_N;
    unsigned short* ao_lo = ao_hi + (size_t)MROWS * CDIM;
    unsigned short* ws_end = ao_lo + (size_t)MROWS * CDIM;

    size_t base_bytes = (size_t)((char*)ws_end - (char*)d_ws);
    const size_t part_bytes = (size_t)ROWS_ALL * (64 + 2) * 4;  // O + m + l per split
    int S = 1;
    if (base_bytes + 4 * part_bytes <= ws_size) S = 4;
    else if (base_bytes + 2 * part_bytes <= ws_size) S = 2;

    float* Opart = (float*)ws_end;                          // base offset is 16B-aligned
    float* mpart = Opart + (size_t)S * ROWS_ALL * 64;
    float* lpart = mpart + (size_t)S * ROWS_ALL;

    ln_split_kernel<<<MROWS, 128, 0, stream>>>(x, ln_g, ln_b, xn_hi, xn_lo);
    wsplit_kernel<<<dim3(8, 8, 4), 256, 0, stream>>>(wq, wk, wv, wo, BTqkv, BTo);

    // fused QKV projection: M=4096, N=1536, K'=1536  (m97 128x128 tile)
    gemm_split_kernel<128><<<dim3(QKV_N / 128, MROWS / 128), 256, 0, stream>>>(
        xn_hi, xn_lo, BTqkv, bq, bk, bv, qkvb, nullptr);

    if (S > 1) {
        attn_kernel<<<dim3(BH, SEQ_N / 128, S), 512, 0, stream>>>(
            qkvb, mask, Opart, mpart, lpart, nullptr, nullptr);
        combine_kernel<<<ROWS_ALL / 32, 256, 0, stream>>>(
            Opart, mpart, lpart, S, ao_hi, ao_lo);
    } else {
        attn_kernel<<<dim3(BH, SEQ_N / 128, 1), 512, 0, stream>>>(
            qkvb, mask, nullptr, nullptr, nullptr, ao_hi, ao_lo);
    }

    // output projection: M=4096, N=512, K'=1536  (BN=64 -> 256 blocks, full GPU)
    gemm_split_kernel<64><<<dim3(CDIM / 64, MROWS / 128), 256, 0, stream>>>(
        ao_hi, ao_lo, BTo, bo, nullptr, nullptr, nullptr, out);
}